// Round 7
// baseline (780.845 us; speedup 1.0000x reference)
//
#include <hip/hip_runtime.h>
#include <math.h>

#define W_ 160
#define H_ 128
#define C_ 32
#define D_ 96
#define NPIX (H_*W_)          // 20480

// k_cost tiling: 16x16 output tile, 1 px/thread
#define TH 16
#define TW 16
#define HS 19                 // halo row stride (18 valid cols + 1 pad)
#define NHPTS (18*HS)         // 342
#define CC 16                 // channels per chunk (2 chunks)

// ---------------- workspace layout (floats) ----------------
#define OFF_FEATT   0
#define OFF_PART    1966080
#define OFF_WT      7864320
#define OFF_ROT     7865184

// ---------------------------------------------------------------------------
// blocks 0..239: transpose features (V,C,H,W) -> featT (V,H,W,C)
// block 240: weight transpose + projection prep
__global__ __launch_bounds__(256) void k_prep_transpose(
    const float* __restrict__ f,
    const float* __restrict__ proj,
    const float* __restrict__ wsrc,
    float* __restrict__ fT,
    float* __restrict__ wT,
    float* __restrict__ rotrans)
{
    if (blockIdx.x < 240) {
        int t = blockIdx.x * 256 + threadIdx.x;  // t = v*20480 + y*160 + x
        int v = t / NPIX;
        const float* src = f + v * (C_*NPIX) + (t - v*NPIX);
        float o[32];
        #pragma unroll
        for (int c = 0; c < 32; ++c) o[c] = src[c * NPIX];
        float4* dst = (float4*)(fT + (size_t)t * 32);
        #pragma unroll
        for (int k = 0; k < 8; ++k) dst[k] = ((float4*)o)[k];
        return;
    }

    int t = threadIdx.x;
    // transpose weights [c][kd][kh][kw] -> [kd][kh][kw][c]
    for (int i = t; i < 864; i += 256) {
        int s = i >> 5, c = i & 31;          // s = (kd*3+kh)*3+kw
        wT[i] = wsrc[c * 27 + s];
    }
    if (t == 0) {
        float P[3][16];
        for (int v = 0; v < 3; ++v) {
            const float* E = proj + v * 32;
            const float* K = proj + v * 32 + 16;
            for (int i = 0; i < 3; ++i)
                for (int j = 0; j < 4; ++j)
                    P[v][i*4+j] = K[i*4+0]*E[0*4+j] + K[i*4+1]*E[1*4+j] + K[i*4+2]*E[2*4+j];
            for (int j = 0; j < 4; ++j) P[v][12+j] = E[12+j];
        }
        const float* m = P[0];
        float inv[16];
        inv[0]  =  m[5]*m[10]*m[15] - m[5]*m[11]*m[14] - m[9]*m[6]*m[15] + m[9]*m[7]*m[14] + m[13]*m[6]*m[11] - m[13]*m[7]*m[10];
        inv[4]  = -m[4]*m[10]*m[15] + m[4]*m[11]*m[14] + m[8]*m[6]*m[15] - m[8]*m[7]*m[14] - m[12]*m[6]*m[11] + m[12]*m[7]*m[10];
        inv[8]  =  m[4]*m[9]*m[15]  - m[4]*m[11]*m[13] - m[8]*m[5]*m[15] + m[8]*m[7]*m[13] + m[12]*m[5]*m[11] - m[12]*m[7]*m[9];
        inv[12] = -m[4]*m[9]*m[14]  + m[4]*m[10]*m[13] + m[8]*m[5]*m[14] - m[8]*m[6]*m[13] - m[12]*m[5]*m[10] + m[12]*m[6]*m[9];
        inv[1]  = -m[1]*m[10]*m[15] + m[1]*m[11]*m[14] + m[9]*m[2]*m[15] - m[9]*m[3]*m[14] - m[13]*m[2]*m[11] + m[13]*m[3]*m[10];
        inv[5]  =  m[0]*m[10]*m[15] - m[0]*m[11]*m[14] - m[8]*m[2]*m[15] + m[8]*m[3]*m[14] + m[12]*m[2]*m[11] - m[12]*m[3]*m[10];
        inv[9]  = -m[0]*m[9]*m[15]  + m[0]*m[11]*m[13] + m[8]*m[1]*m[15] - m[8]*m[3]*m[13] - m[12]*m[1]*m[11] + m[12]*m[3]*m[9];
        inv[13] =  m[0]*m[9]*m[14]  - m[0]*m[10]*m[13] - m[8]*m[1]*m[14] + m[8]*m[2]*m[13] + m[12]*m[1]*m[10] - m[12]*m[2]*m[9];
        inv[2]  =  m[1]*m[6]*m[15]  - m[1]*m[7]*m[14]  - m[5]*m[2]*m[15] + m[5]*m[3]*m[14] + m[13]*m[2]*m[7]  - m[13]*m[3]*m[6];
        inv[6]  = -m[0]*m[6]*m[15]  + m[0]*m[7]*m[14]  + m[4]*m[2]*m[15] - m[4]*m[3]*m[14] - m[12]*m[2]*m[7]  + m[12]*m[3]*m[6];
        inv[10] =  m[0]*m[5]*m[15]  - m[0]*m[7]*m[13]  - m[4]*m[1]*m[15] + m[4]*m[3]*m[13] + m[12]*m[1]*m[7]  - m[12]*m[3]*m[5];
        inv[14] = -m[0]*m[5]*m[14]  + m[0]*m[6]*m[13]  + m[4]*m[1]*m[14] - m[4]*m[2]*m[13] - m[12]*m[1]*m[6]  + m[12]*m[2]*m[5];
        inv[3]  = -m[1]*m[6]*m[11]  + m[1]*m[7]*m[10]  + m[5]*m[2]*m[11] - m[5]*m[3]*m[10] - m[9]*m[2]*m[7]   + m[9]*m[3]*m[6];
        inv[7]  =  m[0]*m[6]*m[11]  - m[0]*m[7]*m[10]  - m[4]*m[2]*m[11] + m[4]*m[3]*m[10] + m[8]*m[2]*m[7]   - m[8]*m[3]*m[6];
        inv[11] = -m[0]*m[5]*m[11]  + m[0]*m[7]*m[9]   + m[4]*m[1]*m[11] - m[4]*m[3]*m[9]  - m[8]*m[1]*m[7]   + m[8]*m[3]*m[5];
        inv[15] =  m[0]*m[5]*m[10]  - m[0]*m[6]*m[9]   - m[4]*m[1]*m[10] + m[4]*m[2]*m[9]  + m[8]*m[1]*m[6]   - m[8]*m[2]*m[5];
        float det = m[0]*inv[0] + m[1]*inv[4] + m[2]*inv[8] + m[3]*inv[12];
        float rdet = 1.0f / det;
        for (int i = 0; i < 16; ++i) inv[i] *= rdet;

        for (int v = 1; v < 3; ++v) {
            float M[16];
            for (int i = 0; i < 4; ++i)
                for (int j = 0; j < 4; ++j) {
                    float a = 0.f;
                    for (int k = 0; k < 4; ++k) a += P[v][i*4+k] * inv[k*4+j];
                    M[i*4+j] = a;
                }
            float* o = rotrans + (v-1)*12;
            for (int i = 0; i < 3; ++i) {
                for (int j = 0; j < 3; ++j) o[i*3+j] = M[i*4+j];
                o[9+i] = M[i*4+3];
            }
        }
    }
}

// ---------------------------------------------------------------------------
// 16x16 tile per block, 1 px/thread, 2 chunks of 16 channels.
// Chunk-invariant sampling state (weights+addresses) hoisted into registers.
// __launch_bounds__(256,4): VGPR cap 128 -> no spill (r6: cap 102 gave VGPR=48
// and 245 MB/thread-aggregate scratch traffic -> 669us regression).
__global__ __launch_bounds__(256, 4) void k_cost(
    const float* __restrict__ featT,
    const float* __restrict__ rotrans_g,
    const float* __restrict__ wT,
    const float* __restrict__ dvals,
    float* __restrict__ part)
{
    __shared__ float4 sVar[NHPTS * 4];   // swizzled slot: p*4 + (c4 ^ ((p>>2)&3))
    __shared__ float4 sW4[216];          // [kd][kh][kw][c/4]
    __shared__ float  sRT[24];

    const int tid = threadIdx.x;
    const int bx = blockIdx.x, by = blockIdx.y, ds = blockIdx.z;

    for (int i = tid; i < 216; i += 256) sW4[i] = ((const float4*)wT)[i];
    if (tid < 24) sRT[tid] = rotrans_g[tid];
    const float dv = dvals[ds];
    __syncthreads();                     // sRT ready for hoist phase

    // ---- hoist chunk-invariant per-point sampling state ----
    // cls: 0 = normal, 1 = zero-write (outside image), 2 = skip (pad col / p>=NHPTS)
    int   cls[2];
    int   rbase[2];                       // ref pixel float4-base (no chunk off)
    float hw[2][2][4];                    // [pt][view][corner] masked weights
    int   hb[2][2][4];                    // [pt][view][corner] float4-base
    #pragma unroll
    for (int pi = 0; pi < 2; ++pi) {
        cls[pi] = 2;
        const int p = tid + pi * 256;
        if (p >= NHPTS) continue;
        const int py = p / HS;
        const int px = p - py * HS;
        if (px >= 18) continue;              // pad column, never read
        const int gy = by * TH + py - 1;
        const int gx = bx * TW + px - 1;
        if (gy < 0 || gy >= H_ || gx < 0 || gx >= W_) { cls[pi] = 1; continue; }
        cls[pi] = 0;
        rbase[pi] = (gy * W_ + gx) * 8;      // *C_/4
        const float xf = (float)gx, yf = (float)gy;
        #pragma unroll
        for (int v = 0; v < 2; ++v) {
            const float* rt = &sRT[v * 12];
            float A0 = rt[0]*xf + rt[1]*yf + rt[2];
            float A1 = rt[3]*xf + rt[4]*yf + rt[5];
            float A2 = rt[6]*xf + rt[7]*yf + rt[8];
            float X = A0 * dv + rt[9];
            float Y = A1 * dv + rt[10];
            float Z = A2 * dv + rt[11];
            float rz = __builtin_amdgcn_rcpf(Z);   // validated in round-2 pass
            float pxf = X * rz, pyf = Y * rz;
            float x0f = floorf(pxf), y0f = floorf(pyf);
            float fx = pxf - x0f, fy = pyf - y0f;
            float w00 = (1.f-fx)*(1.f-fy), w10 = fx*(1.f-fy);
            float w01 = (1.f-fx)*fy,       w11 = fx*fy;
            float x1f = x0f + 1.f, y1f = y0f + 1.f;
            bool vx0 = (x0f >= 0.f) && (x0f <= (float)(W_-1));
            bool vx1 = (x1f >= 0.f) && (x1f <= (float)(W_-1));
            bool vy0 = (y0f >= 0.f) && (y0f <= (float)(H_-1));
            bool vy1 = (y1f >= 0.f) && (y1f <= (float)(H_-1));
            hw[pi][v][0] = (vx0 && vy0) ? w00 : 0.f;
            hw[pi][v][1] = (vx1 && vy0) ? w10 : 0.f;
            hw[pi][v][2] = (vx0 && vy1) ? w01 : 0.f;
            hw[pi][v][3] = (vx1 && vy1) ? w11 : 0.f;
            int xc0 = (int)fminf(fmaxf(x0f, 0.f), (float)(W_-1));
            int xc1 = (int)fminf(fmaxf(x1f, 0.f), (float)(W_-1));
            int yc0 = (int)fminf(fmaxf(y0f, 0.f), (float)(H_-1));
            int yc1 = (int)fminf(fmaxf(y1f, 0.f), (float)(H_-1));
            const int vb = (v + 1) * H_;
            hb[pi][v][0] = ((vb + yc0) * W_ + xc0) * 8;
            hb[pi][v][1] = ((vb + yc0) * W_ + xc1) * 8;
            hb[pi][v][2] = ((vb + yc1) * W_ + xc0) * 8;
            hb[pi][v][3] = ((vb + yc1) * W_ + xc1) * 8;
        }
    }

    float acc[3] = {0.f, 0.f, 0.f};
    const float4* fp = (const float4*)featT;
    const float inv3 = 1.f / 3.f;

    for (int chunk = 0; chunk < 2; ++chunk) {
        const int cb = chunk * 4;        // float4 offset within pixel
        __syncthreads();                  // protect LDS from previous conv reads
        // ---- fill variance halo tile (16 channels): pure load+blend ----
        #pragma unroll
        for (int pi = 0; pi < 2; ++pi) {
            if (cls[pi] == 2) continue;
            const int p = tid + pi * 256;
            if (cls[pi] == 1) {
                #pragma unroll
                for (int c4 = 0; c4 < 4; ++c4)
                    sVar[(p << 2) + (c4 ^ ((p >> 2) & 3))] = make_float4(0.f,0.f,0.f,0.f);
                continue;
            }
            float4 s[4], q[4];
            #pragma unroll
            for (int c4 = 0; c4 < 4; ++c4) {
                float4 f = fp[rbase[pi] + cb + c4];
                s[c4] = f;
                q[c4] = make_float4(f.x*f.x, f.y*f.y, f.z*f.z, f.w*f.w);
            }
            #pragma unroll
            for (int v = 0; v < 2; ++v) {
                const float w00 = hw[pi][v][0], w10 = hw[pi][v][1];
                const float w01 = hw[pi][v][2], w11 = hw[pi][v][3];
                const int b00 = hb[pi][v][0] + cb, b10 = hb[pi][v][1] + cb;
                const int b01 = hb[pi][v][2] + cb, b11 = hb[pi][v][3] + cb;
                #pragma unroll
                for (int c4 = 0; c4 < 4; ++c4) {
                    float4 f00 = fp[b00 + c4], f10 = fp[b10 + c4];
                    float4 f01 = fp[b01 + c4], f11 = fp[b11 + c4];
                    float wx = w00*f00.x + w10*f10.x + w01*f01.x + w11*f11.x;
                    float wy = w00*f00.y + w10*f10.y + w01*f01.y + w11*f11.y;
                    float wz = w00*f00.z + w10*f10.z + w01*f01.z + w11*f11.z;
                    float ww = w00*f00.w + w10*f10.w + w01*f01.w + w11*f11.w;
                    s[c4].x += wx; s[c4].y += wy; s[c4].z += wz; s[c4].w += ww;
                    q[c4].x += wx*wx; q[c4].y += wy*wy; q[c4].z += wz*wz; q[c4].w += ww*ww;
                }
            }
            #pragma unroll
            for (int c4 = 0; c4 < 4; ++c4) {
                float mx = s[c4].x * inv3, my = s[c4].y * inv3,
                      mz = s[c4].z * inv3, mw = s[c4].w * inv3;
                float4 var = make_float4(q[c4].x*inv3 - mx*mx, q[c4].y*inv3 - my*my,
                                         q[c4].z*inv3 - mz*mz, q[c4].w*inv3 - mw*mw);
                sVar[(p << 2) + (c4 ^ ((p >> 2) & 3))] = var;
            }
        }
        __syncthreads();
        // ---- conv accumulate (3 kd planes, 1 output per thread) ----
        const int ty = tid >> 4;
        const int tx = tid & 15;
        #pragma unroll
        for (int c4 = 0; c4 < 4; ++c4) {
            #pragma unroll
            for (int kh = 0; kh < 3; ++kh) {
                float4 wv[3][3];
                #pragma unroll
                for (int kd = 0; kd < 3; ++kd)
                    #pragma unroll
                    for (int kw = 0; kw < 3; ++kw)
                        wv[kd][kw] = sW4[((kd*3 + kh)*3 + kw) * 8 + chunk*4 + c4];
                float4 vv[3];
                const int rowb = (ty + kh) * HS + tx;
                #pragma unroll
                for (int i = 0; i < 3; ++i) {
                    int p = rowb + i;
                    vv[i] = sVar[(p << 2) + (c4 ^ ((p >> 2) & 3))];
                }
                #pragma unroll
                for (int kd = 0; kd < 3; ++kd)
                    #pragma unroll
                    for (int kw = 0; kw < 3; ++kw) {
                        float4 a = vv[kw];
                        float4 b = wv[kd][kw];
                        acc[kd] += a.x*b.x + a.y*b.y + a.z*b.z + a.w*b.w;
                    }
            }
        }
    }
    const int oy = by * TH + (tid >> 4);
    const int ox = bx * TW + (tid & 15);
    #pragma unroll
    for (int kd = 0; kd < 3; ++kd)
        part[(size_t)(kd * D_ + ds) * NPIX + oy * W_ + ox] = acc[kd];
}

// ---------------------------------------------------------------------------
__global__ __launch_bounds__(256) void k_softmax(
    const float* __restrict__ part,
    const float* __restrict__ dvals,
    const float* __restrict__ bias,
    float* __restrict__ out)
{
    __shared__ float sD[96];
    if (threadIdx.x < 96) sD[threadIdx.x] = dvals[threadIdx.x];
    __syncthreads();

    int pix = blockIdx.x * 256 + threadIdx.x;
    if (pix >= NPIX) return;
    float e[96];
    const float b = bias[0];
    float m = -1e30f;
    #pragma unroll
    for (int d = 0; d < 96; ++d) {
        float c = part[(size_t)(D_ + d) * NPIX + pix];              // kd=1 plane
        if (d > 0)  c += part[(size_t)(d - 1) * NPIX + pix];        // kd=0 plane
        if (d < 95) c += part[(size_t)(2*D_ + d + 1) * NPIX + pix]; // kd=2 plane
        c += b;
        e[d] = c;
        m = fmaxf(m, c);
    }
    float sum = 0.f, dsum = 0.f, isum = 0.f;
    #pragma unroll
    for (int d = 0; d < 96; ++d) {
        float ex = __expf(e[d] - m);
        e[d] = ex;
        sum  += ex;
        dsum += ex * sD[d];
        isum += ex * (float)d;
    }
    float inv = 1.f / sum;
    float depth = dsum * inv;
    float idxf = isum * inv;
    int di = (int)idxf;
    di = di < 0 ? 0 : (di > 95 ? 95 : di);
    float cs = 0.f;
    #pragma unroll
    for (int d = 0; d < 96; ++d) {
        bool in = (d >= di - 1) && (d <= di + 2);
        cs += in ? e[d] : 0.f;
    }
    out[pix] = depth;
    out[NPIX + pix] = cs * inv;
}

// ---------------------------------------------------------------------------
extern "C" void kernel_launch(void* const* d_in, const int* in_sizes, int n_in,
                              void* d_out, int out_size, void* d_ws, size_t ws_size,
                              hipStream_t stream)
{
    const float* features = (const float*)d_in[0];
    const float* proj     = (const float*)d_in[1];
    const float* dvals    = (const float*)d_in[2];
    const float* wsrc     = (const float*)d_in[3];
    const float* bias     = (const float*)d_in[4];
    float* ws = (float*)d_ws;
    float* featT   = ws + OFF_FEATT;
    float* part    = ws + OFF_PART;
    float* wT      = ws + OFF_WT;
    float* rotrans = ws + OFF_ROT;
    float* out = (float*)d_out;

    hipLaunchKernelGGL(k_prep_transpose, dim3(241), dim3(256), 0, stream,
                       features, proj, wsrc, featT, wT, rotrans);
    hipLaunchKernelGGL(k_cost, dim3(10, 8, 96), dim3(256), 0, stream,
                       featT, rotrans, wT, dvals, part);
    hipLaunchKernelGGL(k_softmax, dim3(80), dim3(256), 0, stream, part, dvals, bias, out);
}

// Round 8
// 581.741 us; speedup vs baseline: 1.3423x; 1.3423x over previous
//
#include <hip/hip_runtime.h>
#include <math.h>

#define W_ 160
#define H_ 128
#define C_ 32
#define D_ 96
#define NPIX (H_*W_)          // 20480

// ---------------- workspace layout ----------------
// floats: featT @0 (1,966,080) | part @1,966,080 (5,898,240) | wT @7,864,320 (864) | rot @7,865,184 (24)
// bytes : var (fp16, packed uints) @ 31,461,376, size 125,829,120
#define OFF_FEATT   0
#define OFF_PART    1966080
#define OFF_WT      7864320
#define OFF_ROT     7865184
#define OFF_VAR_BYTES  31461376ull
#define VAR_BYTES      125829120ull
#define REQ_WS         (OFF_VAR_BYTES + VAR_BYTES)

typedef unsigned int uint;

__device__ inline uint pack2(float a, float b) {
    unsigned short ua = __builtin_bit_cast(unsigned short, (_Float16)a);
    unsigned short ub = __builtin_bit_cast(unsigned short, (_Float16)b);
    return (uint)ua | ((uint)ub << 16);
}
__device__ inline float f16lo(uint u){ return (float)__builtin_bit_cast(_Float16,(unsigned short)(u & 0xffffu)); }
__device__ inline float f16hi(uint u){ return (float)__builtin_bit_cast(_Float16,(unsigned short)(u >> 16)); }

// ---------------------------------------------------------------------------
// blocks 0..239: transpose features (V,C,H,W) -> featT (V,H,W,C)
// block 240: weight transpose + projection prep
__global__ __launch_bounds__(256) void k_prep_transpose(
    const float* __restrict__ f,
    const float* __restrict__ proj,
    const float* __restrict__ wsrc,
    float* __restrict__ fT,
    float* __restrict__ wT,
    float* __restrict__ rotrans)
{
    if (blockIdx.x < 240) {
        int t = blockIdx.x * 256 + threadIdx.x;  // t = v*20480 + y*160 + x
        int v = t / NPIX;
        const float* src = f + v * (C_*NPIX) + (t - v*NPIX);
        float o[32];
        #pragma unroll
        for (int c = 0; c < 32; ++c) o[c] = src[c * NPIX];
        float4* dst = (float4*)(fT + (size_t)t * 32);
        #pragma unroll
        for (int k = 0; k < 8; ++k) dst[k] = ((float4*)o)[k];
        return;
    }

    int t = threadIdx.x;
    for (int i = t; i < 864; i += 256) {
        int s = i >> 5, c = i & 31;          // s = (kd*3+kh)*3+kw
        wT[i] = wsrc[c * 27 + s];
    }
    if (t == 0) {
        float P[3][16];
        for (int v = 0; v < 3; ++v) {
            const float* E = proj + v * 32;
            const float* K = proj + v * 32 + 16;
            for (int i = 0; i < 3; ++i)
                for (int j = 0; j < 4; ++j)
                    P[v][i*4+j] = K[i*4+0]*E[0*4+j] + K[i*4+1]*E[1*4+j] + K[i*4+2]*E[2*4+j];
            for (int j = 0; j < 4; ++j) P[v][12+j] = E[12+j];
        }
        const float* m = P[0];
        float inv[16];
        inv[0]  =  m[5]*m[10]*m[15] - m[5]*m[11]*m[14] - m[9]*m[6]*m[15] + m[9]*m[7]*m[14] + m[13]*m[6]*m[11] - m[13]*m[7]*m[10];
        inv[4]  = -m[4]*m[10]*m[15] + m[4]*m[11]*m[14] + m[8]*m[6]*m[15] - m[8]*m[7]*m[14] - m[12]*m[6]*m[11] + m[12]*m[7]*m[10];
        inv[8]  =  m[4]*m[9]*m[15]  - m[4]*m[11]*m[13] - m[8]*m[5]*m[15] + m[8]*m[7]*m[13] + m[12]*m[5]*m[11] - m[12]*m[7]*m[9];
        inv[12] = -m[4]*m[9]*m[14]  + m[4]*m[10]*m[13] + m[8]*m[5]*m[14] - m[8]*m[6]*m[13] - m[12]*m[5]*m[10] + m[12]*m[6]*m[9];
        inv[1]  = -m[1]*m[10]*m[15] + m[1]*m[11]*m[14] + m[9]*m[2]*m[15] - m[9]*m[3]*m[14] - m[13]*m[2]*m[11] + m[13]*m[3]*m[10];
        inv[5]  =  m[0]*m[10]*m[15] - m[0]*m[11]*m[14] - m[8]*m[2]*m[15] + m[8]*m[3]*m[14] + m[12]*m[2]*m[11] - m[12]*m[3]*m[10];
        inv[9]  = -m[0]*m[9]*m[15]  + m[0]*m[11]*m[13] + m[8]*m[1]*m[15] - m[8]*m[3]*m[13] - m[12]*m[1]*m[11] + m[12]*m[3]*m[9];
        inv[13] =  m[0]*m[9]*m[14]  - m[0]*m[10]*m[13] - m[8]*m[1]*m[14] + m[8]*m[2]*m[13] + m[12]*m[1]*m[10] - m[12]*m[2]*m[9];
        inv[2]  =  m[1]*m[6]*m[15]  - m[1]*m[7]*m[14]  - m[5]*m[2]*m[15] + m[5]*m[3]*m[14] + m[13]*m[2]*m[7]  - m[13]*m[3]*m[6];
        inv[6]  = -m[0]*m[6]*m[15]  + m[0]*m[7]*m[14]  + m[4]*m[2]*m[15] - m[4]*m[3]*m[14] - m[12]*m[2]*m[7]  + m[12]*m[3]*m[6];
        inv[10] =  m[0]*m[5]*m[15]  - m[0]*m[7]*m[13]  - m[4]*m[1]*m[15] + m[4]*m[3]*m[13] + m[12]*m[1]*m[7]  - m[12]*m[3]*m[5];
        inv[14] = -m[0]*m[5]*m[14]  + m[0]*m[6]*m[13]  + m[4]*m[1]*m[14] - m[4]*m[2]*m[13] - m[12]*m[1]*m[6]  + m[12]*m[2]*m[5];
        inv[3]  = -m[1]*m[6]*m[11]  + m[1]*m[7]*m[10]  + m[5]*m[2]*m[11] - m[5]*m[3]*m[10] - m[9]*m[2]*m[7]   + m[9]*m[3]*m[6];
        inv[7]  =  m[0]*m[6]*m[11]  - m[0]*m[7]*m[10]  - m[4]*m[2]*m[11] + m[4]*m[3]*m[10] + m[8]*m[2]*m[7]   - m[8]*m[3]*m[6];
        inv[11] = -m[0]*m[5]*m[11]  + m[0]*m[7]*m[9]   + m[4]*m[1]*m[11] - m[4]*m[3]*m[9]  - m[8]*m[1]*m[7]   + m[8]*m[3]*m[5];
        inv[15] =  m[0]*m[5]*m[10]  - m[0]*m[6]*m[9]   - m[4]*m[1]*m[10] + m[4]*m[2]*m[9]  + m[8]*m[1]*m[6]   - m[8]*m[2]*m[5];
        float det = m[0]*inv[0] + m[1]*inv[4] + m[2]*inv[8] + m[3]*inv[12];
        float rdet = 1.0f / det;
        for (int i = 0; i < 16; ++i) inv[i] *= rdet;

        for (int v = 1; v < 3; ++v) {
            float M[16];
            for (int i = 0; i < 4; ++i)
                for (int j = 0; j < 4; ++j) {
                    float a = 0.f;
                    for (int k = 0; k < 4; ++k) a += P[v][i*4+k] * inv[k*4+j];
                    M[i*4+j] = a;
                }
            float* o = rotrans + (v-1)*12;
            for (int i = 0; i < 3; ++i) {
                for (int j = 0; j < 3; ++j) o[i*3+j] = M[i*4+j];
                o[9+i] = M[i*4+3];
            }
        }
    }
}

// ---------------------------------------------------------------------------
// FAST PATH kernel 1: variance volume, fp16. One thread = one (pixel, depth).
// No LDS, no barriers, no halo redundancy. Natural VGPR (no cap -> no spill).
__global__ __launch_bounds__(256) void k_var(
    const float* __restrict__ featT,
    const float* __restrict__ rotrans_g,
    const float* __restrict__ dvals,
    uint* __restrict__ varU)
{
    const int tid = threadIdx.x;
    const int bx = blockIdx.x, by = blockIdx.y, ds = blockIdx.z;
    const int tx = tid & 15, ty = tid >> 4;
    const int gx = bx * 16 + tx, gy = by * 16 + ty;
    const float dv = dvals[ds];
    const float4* fp = (const float4*)featT;
    const int rb = (gy * W_ + gx) * 8;

    // per-view masked weights + corner bases (chunk-invariant, computed once)
    float w[2][4];
    int   b[2][4];
    const float xf = (float)gx, yf = (float)gy;
    #pragma unroll
    for (int v = 0; v < 2; ++v) {
        const float* rt = rotrans_g + v * 12;   // uniform -> s_loads
        float A0 = rt[0]*xf + rt[1]*yf + rt[2];
        float A1 = rt[3]*xf + rt[4]*yf + rt[5];
        float A2 = rt[6]*xf + rt[7]*yf + rt[8];
        float X = A0 * dv + rt[9];
        float Y = A1 * dv + rt[10];
        float Z = A2 * dv + rt[11];
        float rz = __builtin_amdgcn_rcpf(Z);
        float pxf = X * rz, pyf = Y * rz;
        float x0f = floorf(pxf), y0f = floorf(pyf);
        float fx = pxf - x0f, fy = pyf - y0f;
        float w00 = (1.f-fx)*(1.f-fy), w10 = fx*(1.f-fy);
        float w01 = (1.f-fx)*fy,       w11 = fx*fy;
        float x1f = x0f + 1.f, y1f = y0f + 1.f;
        bool vx0 = (x0f >= 0.f) && (x0f <= (float)(W_-1));
        bool vx1 = (x1f >= 0.f) && (x1f <= (float)(W_-1));
        bool vy0 = (y0f >= 0.f) && (y0f <= (float)(H_-1));
        bool vy1 = (y1f >= 0.f) && (y1f <= (float)(H_-1));
        w[v][0] = (vx0 && vy0) ? w00 : 0.f;
        w[v][1] = (vx1 && vy0) ? w10 : 0.f;
        w[v][2] = (vx0 && vy1) ? w01 : 0.f;
        w[v][3] = (vx1 && vy1) ? w11 : 0.f;
        int xc0 = (int)fminf(fmaxf(x0f, 0.f), (float)(W_-1));
        int xc1 = (int)fminf(fmaxf(x1f, 0.f), (float)(W_-1));
        int yc0 = (int)fminf(fmaxf(y0f, 0.f), (float)(H_-1));
        int yc1 = (int)fminf(fmaxf(y1f, 0.f), (float)(H_-1));
        const int vb = (v + 1) * H_;
        b[v][0] = ((vb + yc0) * W_ + xc0) * 8;
        b[v][1] = ((vb + yc0) * W_ + xc1) * 8;
        b[v][2] = ((vb + yc1) * W_ + xc0) * 8;
        b[v][3] = ((vb + yc1) * W_ + xc1) * 8;
    }

    const float inv3 = 1.f / 3.f;
    uint outv[16];
    #pragma unroll
    for (int c4 = 0; c4 < 8; ++c4) {
        float4 f = fp[rb + c4];
        float4 s = f;
        float4 q = make_float4(f.x*f.x, f.y*f.y, f.z*f.z, f.w*f.w);
        #pragma unroll
        for (int v = 0; v < 2; ++v) {
            float4 f00 = fp[b[v][0] + c4], f10 = fp[b[v][1] + c4];
            float4 f01 = fp[b[v][2] + c4], f11 = fp[b[v][3] + c4];
            float wx = w[v][0]*f00.x + w[v][1]*f10.x + w[v][2]*f01.x + w[v][3]*f11.x;
            float wy = w[v][0]*f00.y + w[v][1]*f10.y + w[v][2]*f01.y + w[v][3]*f11.y;
            float wz = w[v][0]*f00.z + w[v][1]*f10.z + w[v][2]*f01.z + w[v][3]*f11.z;
            float ww = w[v][0]*f00.w + w[v][1]*f10.w + w[v][2]*f01.w + w[v][3]*f11.w;
            s.x += wx; s.y += wy; s.z += wz; s.w += ww;
            q.x += wx*wx; q.y += wy*wy; q.z += wz*wz; q.w += ww*ww;
        }
        float mx = s.x*inv3, my = s.y*inv3, mz = s.z*inv3, mw = s.w*inv3;
        float vx = q.x*inv3 - mx*mx, vy = q.y*inv3 - my*my;
        float vz = q.z*inv3 - mz*mz, vw = q.w*inv3 - mw*mw;
        outv[2*c4]   = pack2(vx, vy);
        outv[2*c4+1] = pack2(vz, vw);
    }
    uint4* dst = (uint4*)(varU + ((size_t)ds * NPIX + gy * W_ + gx) * 16);
    #pragma unroll
    for (int j = 0; j < 4; ++j) dst[j] = ((uint4*)outv)[j];
}

// ---------------------------------------------------------------------------
// FAST PATH kernel 2: 3x3x3 conv as 3 kd-plane partials from one var slice.
// Pure LDS stencil: stage 18x18x32ch fp16 tile (80 B/pt stride, conflict-free),
// 1 barrier, 864 FMA/thread.
#define HSB 19
#define NHP (18*HSB)   // 342
#define PSTR 20        // uints per point in LDS (16 data + 4 pad)

__global__ __launch_bounds__(256) void k_conv(
    const uint* __restrict__ varU,
    const float* __restrict__ wT,
    float* __restrict__ part)
{
    __shared__ uint  sL[NHP * PSTR];   // 27,360 B
    __shared__ float4 sW[216];          // 3,456 B

    const int tid = threadIdx.x;
    const int bx = blockIdx.x, by = blockIdx.y, ds = blockIdx.z;

    for (int i = tid; i < 216; i += 256) sW[i] = ((const float4*)wT)[i];
    #pragma unroll
    for (int pi = 0; pi < 2; ++pi) {
        const int p = tid + pi * 256;
        if (p < NHP) {
            const int py = p / HSB;
            const int px = p - py * HSB;
            if (px < 18) {
                const int gy = by * 16 + py - 1;
                const int gx = bx * 16 + px - 1;
                uint4* d = (uint4*)&sL[p * PSTR];
                if (gy < 0 || gy >= H_ || gx < 0 || gx >= W_) {
                    uint4 z = make_uint4(0u,0u,0u,0u);
                    d[0] = z; d[1] = z; d[2] = z; d[3] = z;
                } else {
                    const uint4* g = (const uint4*)(varU + ((size_t)ds * NPIX + gy * W_ + gx) * 16);
                    d[0] = g[0]; d[1] = g[1]; d[2] = g[2]; d[3] = g[3];
                }
            }
        }
    }
    __syncthreads();

    const int ty = tid >> 4, tx = tid & 15;
    float acc[3] = {0.f, 0.f, 0.f};
    #pragma unroll
    for (int c4 = 0; c4 < 8; ++c4) {
        #pragma unroll
        for (int kh = 0; kh < 3; ++kh) {
            float4 wv[3][3];
            #pragma unroll
            for (int kd = 0; kd < 3; ++kd)
                #pragma unroll
                for (int kw = 0; kw < 3; ++kw)
                    wv[kd][kw] = sW[((kd*3 + kh)*3 + kw) * 8 + c4];
            const int rowb = (ty + kh) * HSB + tx;
            #pragma unroll
            for (int kw = 0; kw < 3; ++kw) {
                const uint* u = &sL[(rowb + kw) * PSTR + c4 * 2];
                uint u0 = u[0], u1 = u[1];
                float f0 = f16lo(u0), f1 = f16hi(u0);
                float f2 = f16lo(u1), f3 = f16hi(u1);
                #pragma unroll
                for (int kd = 0; kd < 3; ++kd)
                    acc[kd] += f0*wv[kd][kw].x + f1*wv[kd][kw].y
                             + f2*wv[kd][kw].z + f3*wv[kd][kw].w;
            }
        }
    }
    const int oy = by * 16 + ty;
    const int ox = bx * 16 + tx;
    #pragma unroll
    for (int kd = 0; kd < 3; ++kd)
        part[(size_t)(kd * D_ + ds) * NPIX + oy * W_ + ox] = acc[kd];
}

// ---------------------------------------------------------------------------
// FALLBACK (ws too small): round-2-style monolithic kernel, natural VGPR.
#define HS 19
#define NHPTS (18*HS)
__global__ __launch_bounds__(256) void k_cost_fb(
    const float* __restrict__ featT,
    const float* __restrict__ rotrans_g,
    const float* __restrict__ wT,
    const float* __restrict__ dvals,
    float* __restrict__ part)
{
    __shared__ float4 sVar[NHPTS * 4];
    __shared__ float4 sW4[216];
    __shared__ float  sRT[24];

    const int tid = threadIdx.x;
    const int bx = blockIdx.x, by = blockIdx.y, ds = blockIdx.z;

    for (int i = tid; i < 216; i += 256) sW4[i] = ((const float4*)wT)[i];
    if (tid < 24) sRT[tid] = rotrans_g[tid];
    const float dv = dvals[ds];
    const int ty = tid >> 4, tx = tid & 15;
    float acc[3] = {0.f, 0.f, 0.f};
    const float4* fp = (const float4*)featT;

    for (int chunk = 0; chunk < 2; ++chunk) {
        const int c0 = chunk * 16;
        __syncthreads();
        for (int p = tid; p < NHPTS; p += 256) {
            const int py = p / HS;
            const int px = p - py * HS;
            if (px >= 18) continue;
            const int gy = by * 16 + py - 1;
            const int gx = bx * 16 + px - 1;
            float4 var[4];
            if (gy < 0 || gy >= H_ || gx < 0 || gx >= W_) {
                #pragma unroll
                for (int c4 = 0; c4 < 4; ++c4) var[c4] = make_float4(0.f,0.f,0.f,0.f);
            } else {
                float4 s[4], q[4];
                const int rbase = ((gy * W_ + gx) * C_ + c0) >> 2;
                #pragma unroll
                for (int c4 = 0; c4 < 4; ++c4) {
                    float4 f = fp[rbase + c4];
                    s[c4] = f;
                    q[c4] = make_float4(f.x*f.x, f.y*f.y, f.z*f.z, f.w*f.w);
                }
                const float xf = (float)gx, yf = (float)gy;
                #pragma unroll
                for (int v = 0; v < 2; ++v) {
                    const float* rt = &sRT[v * 12];
                    float A0 = rt[0]*xf + rt[1]*yf + rt[2];
                    float A1 = rt[3]*xf + rt[4]*yf + rt[5];
                    float A2 = rt[6]*xf + rt[7]*yf + rt[8];
                    float X = A0 * dv + rt[9];
                    float Y = A1 * dv + rt[10];
                    float Z = A2 * dv + rt[11];
                    float rz = __builtin_amdgcn_rcpf(Z);
                    float pxf = X * rz, pyf = Y * rz;
                    float x0f = floorf(pxf), y0f = floorf(pyf);
                    float fx = pxf - x0f, fy = pyf - y0f;
                    float w00 = (1.f-fx)*(1.f-fy), w10 = fx*(1.f-fy);
                    float w01 = (1.f-fx)*fy,       w11 = fx*fy;
                    float x1f = x0f + 1.f, y1f = y0f + 1.f;
                    bool vx0 = (x0f >= 0.f) && (x0f <= (float)(W_-1));
                    bool vx1 = (x1f >= 0.f) && (x1f <= (float)(W_-1));
                    bool vy0 = (y0f >= 0.f) && (y0f <= (float)(H_-1));
                    bool vy1 = (y1f >= 0.f) && (y1f <= (float)(H_-1));
                    w00 = (vx0 && vy0) ? w00 : 0.f;
                    w10 = (vx1 && vy0) ? w10 : 0.f;
                    w01 = (vx0 && vy1) ? w01 : 0.f;
                    w11 = (vx1 && vy1) ? w11 : 0.f;
                    int xc0 = (int)fminf(fmaxf(x0f, 0.f), (float)(W_-1));
                    int xc1 = (int)fminf(fmaxf(x1f, 0.f), (float)(W_-1));
                    int yc0 = (int)fminf(fmaxf(y0f, 0.f), (float)(H_-1));
                    int yc1 = (int)fminf(fmaxf(y1f, 0.f), (float)(H_-1));
                    const int vb = (v + 1) * H_;
                    int b00 = (((vb + yc0) * W_ + xc0) * C_ + c0) >> 2;
                    int b10 = (((vb + yc0) * W_ + xc1) * C_ + c0) >> 2;
                    int b01 = (((vb + yc1) * W_ + xc0) * C_ + c0) >> 2;
                    int b11 = (((vb + yc1) * W_ + xc1) * C_ + c0) >> 2;
                    #pragma unroll
                    for (int c4 = 0; c4 < 4; ++c4) {
                        float4 f00 = fp[b00 + c4], f10 = fp[b10 + c4];
                        float4 f01 = fp[b01 + c4], f11 = fp[b11 + c4];
                        float wx = w00*f00.x + w10*f10.x + w01*f01.x + w11*f11.x;
                        float wy = w00*f00.y + w10*f10.y + w01*f01.y + w11*f11.y;
                        float wz = w00*f00.z + w10*f10.z + w01*f01.z + w11*f11.z;
                        float ww = w00*f00.w + w10*f10.w + w01*f01.w + w11*f11.w;
                        s[c4].x += wx; s[c4].y += wy; s[c4].z += wz; s[c4].w += ww;
                        q[c4].x += wx*wx; q[c4].y += wy*wy; q[c4].z += wz*wz; q[c4].w += ww*ww;
                    }
                }
                const float inv3 = 1.f / 3.f;
                #pragma unroll
                for (int c4 = 0; c4 < 4; ++c4) {
                    float mx = s[c4].x * inv3, my = s[c4].y * inv3,
                          mz = s[c4].z * inv3, mw = s[c4].w * inv3;
                    var[c4] = make_float4(q[c4].x*inv3 - mx*mx, q[c4].y*inv3 - my*my,
                                          q[c4].z*inv3 - mz*mz, q[c4].w*inv3 - mw*mw);
                }
            }
            #pragma unroll
            for (int c4 = 0; c4 < 4; ++c4)
                sVar[(p << 2) + (c4 ^ ((p >> 2) & 3))] = var[c4];
        }
        __syncthreads();
        #pragma unroll
        for (int c4 = 0; c4 < 4; ++c4) {
            #pragma unroll
            for (int kh = 0; kh < 3; ++kh) {
                float4 wv[3][3];
                #pragma unroll
                for (int kd = 0; kd < 3; ++kd)
                    #pragma unroll
                    for (int kw = 0; kw < 3; ++kw)
                        wv[kd][kw] = sW4[((kd*3 + kh)*3 + kw) * 8 + chunk*4 + c4];
                float4 vv[3];
                const int rowb = (ty + kh) * HS + tx;
                #pragma unroll
                for (int i = 0; i < 3; ++i) {
                    int p = rowb + i;
                    vv[i] = sVar[(p << 2) + (c4 ^ ((p >> 2) & 3))];
                }
                #pragma unroll
                for (int kd = 0; kd < 3; ++kd)
                    #pragma unroll
                    for (int kw = 0; kw < 3; ++kw) {
                        float4 a = vv[kw];
                        float4 b = wv[kd][kw];
                        acc[kd] += a.x*b.x + a.y*b.y + a.z*b.z + a.w*b.w;
                    }
            }
        }
    }
    const int oy = by * 16 + ty;
    const int ox = bx * 16 + tx;
    #pragma unroll
    for (int kd = 0; kd < 3; ++kd)
        part[(size_t)(kd * D_ + ds) * NPIX + oy * W_ + ox] = acc[kd];
}

// ---------------------------------------------------------------------------
__global__ __launch_bounds__(256) void k_softmax(
    const float* __restrict__ part,
    const float* __restrict__ dvals,
    const float* __restrict__ bias,
    float* __restrict__ out)
{
    __shared__ float sD[96];
    if (threadIdx.x < 96) sD[threadIdx.x] = dvals[threadIdx.x];
    __syncthreads();

    int pix = blockIdx.x * 256 + threadIdx.x;
    if (pix >= NPIX) return;
    float e[96];
    const float b = bias[0];
    float m = -1e30f;
    #pragma unroll
    for (int d = 0; d < 96; ++d) {
        float c = part[(size_t)(D_ + d) * NPIX + pix];              // kd=1 plane
        if (d > 0)  c += part[(size_t)(d - 1) * NPIX + pix];        // kd=0 plane
        if (d < 95) c += part[(size_t)(2*D_ + d + 1) * NPIX + pix]; // kd=2 plane
        c += b;
        e[d] = c;
        m = fmaxf(m, c);
    }
    float sum = 0.f, dsum = 0.f, isum = 0.f;
    #pragma unroll
    for (int d = 0; d < 96; ++d) {
        float ex = __expf(e[d] - m);
        e[d] = ex;
        sum  += ex;
        dsum += ex * sD[d];
        isum += ex * (float)d;
    }
    float inv = 1.f / sum;
    float depth = dsum * inv;
    float idxf = isum * inv;
    int di = (int)idxf;
    di = di < 0 ? 0 : (di > 95 ? 95 : di);
    float cs = 0.f;
    #pragma unroll
    for (int d = 0; d < 96; ++d) {
        bool in = (d >= di - 1) && (d <= di + 2);
        cs += in ? e[d] : 0.f;
    }
    out[pix] = depth;
    out[NPIX + pix] = cs * inv;
}

// ---------------------------------------------------------------------------
extern "C" void kernel_launch(void* const* d_in, const int* in_sizes, int n_in,
                              void* d_out, int out_size, void* d_ws, size_t ws_size,
                              hipStream_t stream)
{
    const float* features = (const float*)d_in[0];
    const float* proj     = (const float*)d_in[1];
    const float* dvals    = (const float*)d_in[2];
    const float* wsrc     = (const float*)d_in[3];
    const float* bias     = (const float*)d_in[4];
    float* ws = (float*)d_ws;
    float* featT   = ws + OFF_FEATT;
    float* part    = ws + OFF_PART;
    float* wT      = ws + OFF_WT;
    float* rotrans = ws + OFF_ROT;
    float* out = (float*)d_out;

    hipLaunchKernelGGL(k_prep_transpose, dim3(241), dim3(256), 0, stream,
                       features, proj, wsrc, featT, wT, rotrans);
    if (ws_size >= REQ_WS) {
        uint* varU = (uint*)((char*)d_ws + OFF_VAR_BYTES);
        hipLaunchKernelGGL(k_var, dim3(10, 8, 96), dim3(256), 0, stream,
                           featT, rotrans, dvals, varU);
        hipLaunchKernelGGL(k_conv, dim3(10, 8, 96), dim3(256), 0, stream,
                           varU, wT, part);
    } else {
        hipLaunchKernelGGL(k_cost_fb, dim3(10, 8, 96), dim3(256), 0, stream,
                           featT, rotrans, wT, dvals, part);
    }
    hipLaunchKernelGGL(k_softmax, dim3(80), dim3(256), 0, stream, part, dvals, bias, out);
}

// Round 9
// 307.242 us; speedup vs baseline: 2.5415x; 1.8934x over previous
//
#include <hip/hip_runtime.h>
#include <math.h>

#define W_ 160
#define H_ 128
#define C_ 32
#define D_ 96
#define NPIX (H_*W_)          // 20480

// ---------------- workspace layout ----------------
// floats: part @0 (5,898,240) | wT @5,898,240 (864) | rot @5,899,104 (24)
// bytes : var (fp16 pairs) @ 23,596,544, size 125,829,120
#define OFF_PART    0
#define OFF_WT      5898240
#define OFF_ROT     5899104
#define OFF_VAR_BYTES  23596544ull
#define VAR_BYTES      125829120ull

typedef unsigned int uint;

__device__ inline uint pack2(float a, float b) {
    unsigned short ua = __builtin_bit_cast(unsigned short, (_Float16)a);
    unsigned short ub = __builtin_bit_cast(unsigned short, (_Float16)b);
    return (uint)ua | ((uint)ub << 16);
}
__device__ inline float f16lo(uint u){ return (float)__builtin_bit_cast(_Float16,(unsigned short)(u & 0xffffu)); }
__device__ inline float f16hi(uint u){ return (float)__builtin_bit_cast(_Float16,(unsigned short)(u >> 16)); }

// ---------------------------------------------------------------------------
// 1 block: weight transpose [c][27] -> [27][c] + projection prep
__global__ __launch_bounds__(256) void k_prep(
    const float* __restrict__ proj,
    const float* __restrict__ wsrc,
    float* __restrict__ wT,
    float* __restrict__ rotrans)
{
    int t = threadIdx.x;
    for (int i = t; i < 864; i += 256) {
        int s = i >> 5, c = i & 31;          // s = (kd*3+kh)*3+kw
        wT[i] = wsrc[c * 27 + s];
    }
    if (t == 0) {
        float P[3][16];
        for (int v = 0; v < 3; ++v) {
            const float* E = proj + v * 32;
            const float* K = proj + v * 32 + 16;
            for (int i = 0; i < 3; ++i)
                for (int j = 0; j < 4; ++j)
                    P[v][i*4+j] = K[i*4+0]*E[0*4+j] + K[i*4+1]*E[1*4+j] + K[i*4+2]*E[2*4+j];
            for (int j = 0; j < 4; ++j) P[v][12+j] = E[12+j];
        }
        const float* m = P[0];
        float inv[16];
        inv[0]  =  m[5]*m[10]*m[15] - m[5]*m[11]*m[14] - m[9]*m[6]*m[15] + m[9]*m[7]*m[14] + m[13]*m[6]*m[11] - m[13]*m[7]*m[10];
        inv[4]  = -m[4]*m[10]*m[15] + m[4]*m[11]*m[14] + m[8]*m[6]*m[15] - m[8]*m[7]*m[14] - m[12]*m[6]*m[11] + m[12]*m[7]*m[10];
        inv[8]  =  m[4]*m[9]*m[15]  - m[4]*m[11]*m[13] - m[8]*m[5]*m[15] + m[8]*m[7]*m[13] + m[12]*m[5]*m[11] - m[12]*m[7]*m[9];
        inv[12] = -m[4]*m[9]*m[14]  + m[4]*m[10]*m[13] + m[8]*m[5]*m[14] - m[8]*m[6]*m[13] - m[12]*m[5]*m[10] + m[12]*m[6]*m[9];
        inv[1]  = -m[1]*m[10]*m[15] + m[1]*m[11]*m[14] + m[9]*m[2]*m[15] - m[9]*m[3]*m[14] - m[13]*m[2]*m[11] + m[13]*m[3]*m[10];
        inv[5]  =  m[0]*m[10]*m[15] - m[0]*m[11]*m[14] - m[8]*m[2]*m[15] + m[8]*m[3]*m[14] + m[12]*m[2]*m[11] - m[12]*m[3]*m[10];
        inv[9]  = -m[0]*m[9]*m[15]  + m[0]*m[11]*m[13] + m[8]*m[1]*m[15] - m[8]*m[3]*m[13] - m[12]*m[1]*m[11] + m[12]*m[3]*m[9];
        inv[13] =  m[0]*m[9]*m[14]  - m[0]*m[10]*m[13] - m[8]*m[1]*m[14] + m[8]*m[2]*m[13] + m[12]*m[1]*m[10] - m[12]*m[2]*m[9];
        inv[2]  =  m[1]*m[6]*m[15]  - m[1]*m[7]*m[14]  - m[5]*m[2]*m[15] + m[5]*m[3]*m[14] + m[13]*m[2]*m[7]  - m[13]*m[3]*m[6];
        inv[6]  = -m[0]*m[6]*m[15]  + m[0]*m[7]*m[14]  + m[4]*m[2]*m[15] - m[4]*m[3]*m[14] - m[12]*m[2]*m[7]  + m[12]*m[3]*m[6];
        inv[10] =  m[0]*m[5]*m[15]  - m[0]*m[7]*m[13]  - m[4]*m[1]*m[15] + m[4]*m[3]*m[13] + m[12]*m[1]*m[7]  - m[12]*m[3]*m[5];
        inv[14] = -m[0]*m[5]*m[14]  + m[0]*m[6]*m[13]  + m[4]*m[1]*m[14] - m[4]*m[2]*m[13] - m[12]*m[1]*m[6]  + m[12]*m[2]*m[5];
        inv[3]  = -m[1]*m[6]*m[11]  + m[1]*m[7]*m[10]  + m[5]*m[2]*m[11] - m[5]*m[3]*m[10] - m[9]*m[2]*m[7]   + m[9]*m[3]*m[6];
        inv[7]  =  m[0]*m[6]*m[11]  - m[0]*m[7]*m[10]  - m[4]*m[2]*m[11] + m[4]*m[3]*m[10] + m[8]*m[2]*m[7]   - m[8]*m[3]*m[6];
        inv[11] = -m[0]*m[5]*m[11]  + m[0]*m[7]*m[9]   + m[4]*m[1]*m[11] - m[4]*m[3]*m[9]  - m[8]*m[1]*m[7]   + m[8]*m[3]*m[5];
        inv[15] =  m[0]*m[5]*m[10]  - m[0]*m[6]*m[9]   - m[4]*m[1]*m[10] + m[4]*m[2]*m[9]  + m[8]*m[1]*m[6]   - m[8]*m[2]*m[5];
        float det = m[0]*inv[0] + m[1]*inv[4] + m[2]*inv[8] + m[3]*inv[12];
        float rdet = 1.0f / det;
        for (int i = 0; i < 16; ++i) inv[i] *= rdet;

        for (int v = 1; v < 3; ++v) {
            float M[16];
            for (int i = 0; i < 4; ++i)
                for (int j = 0; j < 4; ++j) {
                    float a = 0.f;
                    for (int k = 0; k < 4; ++k) a += P[v][i*4+k] * inv[k*4+j];
                    M[i*4+j] = a;
                }
            float* o = rotrans + (v-1)*12;
            for (int i = 0; i < 3; ++i) {
                for (int j = 0; j < 3; ++j) o[i*3+j] = M[i*4+j];
                o[9+i] = M[i*4+3];
            }
        }
    }
}

// ---------------------------------------------------------------------------
// Variance volume from the ORIGINAL channel-major features (V,C,H,W).
// For fixed channel, adjacent lanes read adjacent 4B words -> coalesced
// gathers (r8's pixel-major layout made every gather touch 64 cache lines ->
// 8x L2 over-fetch, 462us at 7.8% VALU). One thread = one (pixel, depth).
__global__ __launch_bounds__(256) void k_var(
    const float* __restrict__ fea,
    const float* __restrict__ rotrans_g,
    const float* __restrict__ dvals,
    uint* __restrict__ varU)
{
    const int tid = threadIdx.x;
    const int bx = blockIdx.x, by = blockIdx.y, ds = blockIdx.z;
    const int tx = tid & 15, ty = tid >> 4;
    const int gx = bx * 16 + tx, gy = by * 16 + ty;
    const float dv = dvals[ds];

    const int ro = gy * W_ + gx;           // ref plane (v=0), channel 0
    float w[2][4];
    int   off[2][4];                       // element offsets incl. view base
    const float xf = (float)gx, yf = (float)gy;
    #pragma unroll
    for (int v = 0; v < 2; ++v) {
        const float* rt = rotrans_g + v * 12;
        float A0 = rt[0]*xf + rt[1]*yf + rt[2];
        float A1 = rt[3]*xf + rt[4]*yf + rt[5];
        float A2 = rt[6]*xf + rt[7]*yf + rt[8];
        float X = A0 * dv + rt[9];
        float Y = A1 * dv + rt[10];
        float Z = A2 * dv + rt[11];
        float rz = __builtin_amdgcn_rcpf(Z);
        float pxf = X * rz, pyf = Y * rz;
        float x0f = floorf(pxf), y0f = floorf(pyf);
        float fx = pxf - x0f, fy = pyf - y0f;
        float w00 = (1.f-fx)*(1.f-fy), w10 = fx*(1.f-fy);
        float w01 = (1.f-fx)*fy,       w11 = fx*fy;
        float x1f = x0f + 1.f, y1f = y0f + 1.f;
        bool vx0 = (x0f >= 0.f) && (x0f <= (float)(W_-1));
        bool vx1 = (x1f >= 0.f) && (x1f <= (float)(W_-1));
        bool vy0 = (y0f >= 0.f) && (y0f <= (float)(H_-1));
        bool vy1 = (y1f >= 0.f) && (y1f <= (float)(H_-1));
        w[v][0] = (vx0 && vy0) ? w00 : 0.f;
        w[v][1] = (vx1 && vy0) ? w10 : 0.f;
        w[v][2] = (vx0 && vy1) ? w01 : 0.f;
        w[v][3] = (vx1 && vy1) ? w11 : 0.f;
        int xc0 = (int)fminf(fmaxf(x0f, 0.f), (float)(W_-1));
        int xc1 = (int)fminf(fmaxf(x1f, 0.f), (float)(W_-1));
        int yc0 = (int)fminf(fmaxf(y0f, 0.f), (float)(H_-1));
        int yc1 = (int)fminf(fmaxf(y1f, 0.f), (float)(H_-1));
        const int vb = (v + 1) * C_ * NPIX;
        off[v][0] = vb + yc0 * W_ + xc0;
        off[v][1] = vb + yc0 * W_ + xc1;
        off[v][2] = vb + yc1 * W_ + xc0;
        off[v][3] = vb + yc1 * W_ + xc1;
    }

    const float inv3 = 1.f / 3.f;
    uint outv[16];
    #pragma unroll
    for (int c2 = 0; c2 < 16; ++c2) {
        float vr[2];
        #pragma unroll
        for (int h = 0; h < 2; ++h) {
            const float* pc = fea + (size_t)(c2 * 2 + h) * NPIX;
            float s = pc[ro];
            float q = s * s;
            #pragma unroll
            for (int v = 0; v < 2; ++v) {
                float f00 = pc[off[v][0]], f10 = pc[off[v][1]];
                float f01 = pc[off[v][2]], f11 = pc[off[v][3]];
                float wf = w[v][0]*f00 + w[v][1]*f10 + w[v][2]*f01 + w[v][3]*f11;
                s += wf;
                q += wf * wf;
            }
            float mm = s * inv3;
            vr[h] = q * inv3 - mm * mm;
        }
        outv[c2] = pack2(vr[0], vr[1]);
    }
    uint4* dst = (uint4*)(varU + ((size_t)ds * NPIX + gy * W_ + gx) * 16);
    #pragma unroll
    for (int j = 0; j < 4; ++j) dst[j] = ((uint4*)outv)[j];
}

// ---------------------------------------------------------------------------
// 3x3x3 conv as 3 kd-plane partials from one var slice (unchanged from r8).
#define HSB 19
#define NHP (18*HSB)   // 342
#define PSTR 20        // uints per point in LDS (16 data + 4 pad)

__global__ __launch_bounds__(256) void k_conv(
    const uint* __restrict__ varU,
    const float* __restrict__ wT,
    float* __restrict__ part)
{
    __shared__ uint  sL[NHP * PSTR];   // 27,360 B
    __shared__ float4 sW[216];          // 3,456 B

    const int tid = threadIdx.x;
    const int bx = blockIdx.x, by = blockIdx.y, ds = blockIdx.z;

    for (int i = tid; i < 216; i += 256) sW[i] = ((const float4*)wT)[i];
    #pragma unroll
    for (int pi = 0; pi < 2; ++pi) {
        const int p = tid + pi * 256;
        if (p < NHP) {
            const int py = p / HSB;
            const int px = p - py * HSB;
            if (px < 18) {
                const int gy = by * 16 + py - 1;
                const int gx = bx * 16 + px - 1;
                uint4* d = (uint4*)&sL[p * PSTR];
                if (gy < 0 || gy >= H_ || gx < 0 || gx >= W_) {
                    uint4 z = make_uint4(0u,0u,0u,0u);
                    d[0] = z; d[1] = z; d[2] = z; d[3] = z;
                } else {
                    const uint4* g = (const uint4*)(varU + ((size_t)ds * NPIX + gy * W_ + gx) * 16);
                    d[0] = g[0]; d[1] = g[1]; d[2] = g[2]; d[3] = g[3];
                }
            }
        }
    }
    __syncthreads();

    const int ty = tid >> 4, tx = tid & 15;
    float acc[3] = {0.f, 0.f, 0.f};
    #pragma unroll
    for (int c4 = 0; c4 < 8; ++c4) {
        #pragma unroll
        for (int kh = 0; kh < 3; ++kh) {
            float4 wv[3][3];
            #pragma unroll
            for (int kd = 0; kd < 3; ++kd)
                #pragma unroll
                for (int kw = 0; kw < 3; ++kw)
                    wv[kd][kw] = sW[((kd*3 + kh)*3 + kw) * 8 + c4];
            const int rowb = (ty + kh) * HSB + tx;
            #pragma unroll
            for (int kw = 0; kw < 3; ++kw) {
                const uint* u = &sL[(rowb + kw) * PSTR + c4 * 2];
                uint u0 = u[0], u1 = u[1];
                float f0 = f16lo(u0), f1 = f16hi(u0);
                float f2 = f16lo(u1), f3 = f16hi(u1);
                #pragma unroll
                for (int kd = 0; kd < 3; ++kd)
                    acc[kd] += f0*wv[kd][kw].x + f1*wv[kd][kw].y
                             + f2*wv[kd][kw].z + f3*wv[kd][kw].w;
            }
        }
    }
    const int oy = by * 16 + ty;
    const int ox = bx * 16 + tx;
    #pragma unroll
    for (int kd = 0; kd < 3; ++kd)
        part[(size_t)(kd * D_ + ds) * NPIX + oy * W_ + ox] = acc[kd];
}

// ---------------------------------------------------------------------------
__global__ __launch_bounds__(256) void k_softmax(
    const float* __restrict__ part,
    const float* __restrict__ dvals,
    const float* __restrict__ bias,
    float* __restrict__ out)
{
    __shared__ float sD[96];
    if (threadIdx.x < 96) sD[threadIdx.x] = dvals[threadIdx.x];
    __syncthreads();

    int pix = blockIdx.x * 256 + threadIdx.x;
    if (pix >= NPIX) return;
    float e[96];
    const float b = bias[0];
    float m = -1e30f;
    #pragma unroll
    for (int d = 0; d < 96; ++d) {
        float c = part[(size_t)(D_ + d) * NPIX + pix];              // kd=1 plane
        if (d > 0)  c += part[(size_t)(d - 1) * NPIX + pix];        // kd=0 plane
        if (d < 95) c += part[(size_t)(2*D_ + d + 1) * NPIX + pix]; // kd=2 plane
        c += b;
        e[d] = c;
        m = fmaxf(m, c);
    }
    float sum = 0.f, dsum = 0.f, isum = 0.f;
    #pragma unroll
    for (int d = 0; d < 96; ++d) {
        float ex = __expf(e[d] - m);
        e[d] = ex;
        sum  += ex;
        dsum += ex * sD[d];
        isum += ex * (float)d;
    }
    float inv = 1.f / sum;
    float depth = dsum * inv;
    float idxf = isum * inv;
    int di = (int)idxf;
    di = di < 0 ? 0 : (di > 95 ? 95 : di);
    float cs = 0.f;
    #pragma unroll
    for (int d = 0; d < 96; ++d) {
        bool in = (d >= di - 1) && (d <= di + 2);
        cs += in ? e[d] : 0.f;
    }
    out[pix] = depth;
    out[NPIX + pix] = cs * inv;
}

// ---------------------------------------------------------------------------
extern "C" void kernel_launch(void* const* d_in, const int* in_sizes, int n_in,
                              void* d_out, int out_size, void* d_ws, size_t ws_size,
                              hipStream_t stream)
{
    const float* features = (const float*)d_in[0];
    const float* proj     = (const float*)d_in[1];
    const float* dvals    = (const float*)d_in[2];
    const float* wsrc     = (const float*)d_in[3];
    const float* bias     = (const float*)d_in[4];
    float* ws = (float*)d_ws;
    float* part    = ws + OFF_PART;
    float* wT      = ws + OFF_WT;
    float* rotrans = ws + OFF_ROT;
    uint*  varU    = (uint*)((char*)d_ws + OFF_VAR_BYTES);
    float* out = (float*)d_out;

    hipLaunchKernelGGL(k_prep, dim3(1), dim3(256), 0, stream, proj, wsrc, wT, rotrans);
    hipLaunchKernelGGL(k_var, dim3(10, 8, 96), dim3(256), 0, stream,
                       features, rotrans, dvals, varU);
    hipLaunchKernelGGL(k_conv, dim3(10, 8, 96), dim3(256), 0, stream,
                       varU, wT, part);
    hipLaunchKernelGGL(k_softmax, dim3(80), dim3(256), 0, stream, part, dvals, bias, out);
}